// Round 6
// baseline (11184.335 us; speedup 1.0000x reference)
//
#include <hip/hip_runtime.h>
#include <math.h>

#define VOCAB 50000
#define DM 256
#define NB 8
#define NK 4
#define SL 24
#define NROW 32
#define RG 8            // rows per block
#define NRG 4           // row groups
#define VBLK 196        // ceil(50000/256)
#define NPART (VBLK*4)  // lse partials per row
#define NCAND (VBLK*4)  // candidates kept per row (4 per vblock)
#define DIVS 0.5f
#define CINV 0x7fffffff

__device__ __forceinline__ bool cbetter(float av, int ai, float bv, int bi) {
  return (av > bv) || (av == bv && ai < bi);
}

__device__ __forceinline__ void merge4(const float* av, const int* ai,
                                       const float* bv, const int* bi,
                                       float* rv, int* ri) {
  int x = 0, y = 0;
#pragma unroll
  for (int j = 0; j < 4; ++j) {
    bool ta = cbetter(av[x], ai[x], bv[y], bi[y]);
    rv[j] = ta ? av[x] : bv[y];
    ri[j] = ta ? ai[x] : bi[y];
    if (ta) ++x; else ++y;
  }
}

// ctx[b][d] = mean_s(src[b,s,:]) @ We
__global__ void k_prep(const float* __restrict__ src, const float* __restrict__ We,
                       float* __restrict__ ctx) {
  int b = blockIdx.x, d = threadIdx.x;
  __shared__ float sm[DM];
  const float* p = src + (size_t)b * 128 * DM + d;
  float s = 0.f;
  for (int i = 0; i < 128; ++i) s += p[i * DM];
  sm[d] = s * (1.f / 128.f);
  __syncthreads();
  float acc = 0.f;
  for (int dp = 0; dp < DM; ++dp) acc += sm[dp] * We[dp * DM + d];
  ctx[b * DM + d] = acc;
}

// Fused: logits (bit-identical FMA chain, never materialized) + per-wave softmax
// partials + per-(row, vblock) top-4 candidates by key = logit - 0.5*pen.
__global__ __launch_bounds__(256) void k_fused(
    const float* __restrict__ Emb, const float* __restrict__ Wout,
    const float* __restrict__ ctx, const int* __restrict__ seq,
    float* __restrict__ pm, float* __restrict__ ps,
    float* __restrict__ ckey, int* __restrict__ cvp,
    const int* __restrict__ minpos, int t, int g) {
  __shared__ __align__(16) float e[RG][DM];
  __shared__ float swv[RG][4][4];
  __shared__ int swi[RG][4][4];
  int tid = threadIdx.x;
  int rg = blockIdx.y;
  for (int r = 0; r < RG; ++r) {
    int rglob = rg * RG + r;
    int tok = seq[rglob * SL + (t - 1)];
    e[r][tid] = Emb[(size_t)tok * DM + tid] + ctx[(rglob >> 2) * DM + tid];
  }
  __syncthreads();
  int v = blockIdx.x * 256 + tid;
  bool valid = (v < VOCAB);
  const float* wcol = Wout + (valid ? v : (VOCAB - 1));
  float acc[RG];
#pragma unroll
  for (int r = 0; r < RG; ++r) acc[r] = 0.f;
  for (int d = 0; d < DM; d += 8) {
    float w0 = wcol[(size_t)d * VOCAB];
    float w1 = wcol[(size_t)(d + 1) * VOCAB];
    float w2 = wcol[(size_t)(d + 2) * VOCAB];
    float w3 = wcol[(size_t)(d + 3) * VOCAB];
    float w4 = wcol[(size_t)(d + 4) * VOCAB];
    float w5 = wcol[(size_t)(d + 5) * VOCAB];
    float w6 = wcol[(size_t)(d + 6) * VOCAB];
    float w7 = wcol[(size_t)(d + 7) * VOCAB];
#pragma unroll
    for (int r = 0; r < RG; ++r) {
      const float4 a4 = *reinterpret_cast<const float4*>(&e[r][d]);
      const float4 b4 = *reinterpret_cast<const float4*>(&e[r][d + 4]);
      acc[r] = fmaf(a4.w, w3, fmaf(a4.z, w2, fmaf(a4.y, w1, fmaf(a4.x, w0, acc[r]))));
      acc[r] = fmaf(b4.w, w7, fmaf(b4.z, w6, fmaf(b4.y, w5, fmaf(b4.x, w4, acc[r]))));
    }
  }
  int lane = tid & 63, wave = tid >> 6;
  // softmax partials (identical structure/order to the passing round-5 kernel)
#pragma unroll
  for (int r = 0; r < RG; ++r) {
    float xm = valid ? acc[r] : -INFINITY;
    float m = xm;
#pragma unroll
    for (int o = 32; o >= 1; o >>= 1) m = fmaxf(m, __shfl_xor(m, o));
    float sv = (m == -INFINITY) ? 0.f : expf(xm - m);
#pragma unroll
    for (int o = 32; o >= 1; o >>= 1) sv += __shfl_xor(sv, o);
    if (lane == 0) {
      int rglob = rg * RG + r;
      int idx = (rglob * VBLK + blockIdx.x) * 4 + wave;
      pm[idx] = m;
      ps[idx] = sv;
    }
  }
  // per-row chunk top-4 by (key desc, vp asc); key = logit - 0.5*pen (exact)
  int pen[NK] = {0, 0, 0, 0};
  if (g && valid) {
#pragma unroll
    for (int k = 0; k < NK; ++k) pen[k] = (minpos[(size_t)k * VOCAB + v] < t) ? 1 : 0;
  }
  for (int r = 0; r < RG; ++r) {
    int kk = r & 3;
    float kv[4]; int vi[4];
    kv[0] = valid ? (acc[r] - (pen[kk] ? 0.5f : 0.0f)) : -INFINITY;
    vi[0] = valid ? (v | (pen[kk] << 16)) : CINV;
#pragma unroll
    for (int j = 1; j < 4; ++j) { kv[j] = -INFINITY; vi[j] = CINV; }
#pragma unroll
    for (int off = 32; off >= 1; off >>= 1) {
      float ov[4]; int oi[4];
#pragma unroll
      for (int j = 0; j < 4; ++j) { ov[j] = __shfl_xor(kv[j], off); oi[j] = __shfl_xor(vi[j], off); }
      float rv2[4]; int ri2[4];
      merge4(kv, vi, ov, oi, rv2, ri2);
#pragma unroll
      for (int j = 0; j < 4; ++j) { kv[j] = rv2[j]; vi[j] = ri2[j]; }
    }
    if (lane == 0) {
#pragma unroll
      for (int j = 0; j < 4; ++j) { swv[r][wave][j] = kv[j]; swi[r][wave][j] = vi[j]; }
    }
  }
  __syncthreads();
  if (tid < RG) {
    int r = tid;
    float m1v[4], m2v[4], mv[4]; int m1i[4], m2i[4], mi[4];
    merge4(swv[r][0], swi[r][0], swv[r][1], swi[r][1], m1v, m1i);
    merge4(swv[r][2], swi[r][2], swv[r][3], swi[r][3], m2v, m2i);
    merge4(m1v, m1i, m2v, m2i, mv, mi);
    int rglob = rg * RG + r;
#pragma unroll
    for (int j = 0; j < 4; ++j) {
      ckey[(size_t)rglob * NCAND + blockIdx.x * 4 + j] = mv[j];
      cvp[(size_t)rglob * NCAND + blockIdx.x * 4 + j] = mi[j];
    }
  }
}

// Final stage per batch: combine lse partials (round-5 order), score 3136
// candidates with the exact passing rounding chain, top-4, seq update.
__global__ __launch_bounds__(256) void k_s2(
    const float* __restrict__ ckey, const int* __restrict__ cvp,
    const float* __restrict__ pm, const float* __restrict__ ps,
    const float* __restrict__ gs_src, const int* __restrict__ seq_src,
    float* __restrict__ gs_dst, int* __restrict__ seq_dst,
    int t, int g, float* __restrict__ out) {
  (void)g;
  int b = blockIdx.x, tid = threadIdx.x;
  int lane = tid & 63, wave = tid >> 6;
  __shared__ float gsv[NK], lsev[NK];
  __shared__ float lv[256][4];
  __shared__ int li[256][4];
  __shared__ int oldseq[NK * SL];
  __shared__ float selv[NK];
  __shared__ int selb[NK], selt[NK];
  if (tid < NK) gsv[tid] = gs_src[b * NK + tid];
  if (tid < NK * SL) oldseq[tid] = seq_src[b * NK * SL + tid];
  // lse combine: wave w -> row b*4+w (same order as passing round-5 code)
  {
    int row = b * NK + wave;
    const float* pmr = pm + (size_t)row * NPART;
    const float* psr = ps + (size_t)row * NPART;
    float M = -INFINITY, S = 0.f;
    for (int j = lane; j < NPART; j += 64) {
      float mj = pmr[j];
      if (mj != -INFINITY) {
        float sj = psr[j];
        float Mn = fmaxf(M, mj);
        S = (M == -INFINITY) ? sj * expf(mj - Mn)
                             : S * expf(M - Mn) + sj * expf(mj - Mn);
        M = Mn;
      }
    }
#pragma unroll
    for (int o = 32; o >= 1; o >>= 1) {
      float Mo = __shfl_xor(M, o);
      float So = __shfl_xor(S, o);
      if (Mo != -INFINITY) {
        float Mn = fmaxf(M, Mo);
        S = (M == -INFINITY) ? So * expf(Mo - Mn)
                             : S * expf(M - Mn) + So * expf(Mo - Mn);
        M = Mn;
      }
    }
    if (lane == 0) lsev[wave] = M + logf(S);
  }
  __syncthreads();

  float tv[4]; int ti[4];
#pragma unroll
  for (int j = 0; j < 4; ++j) { tv[j] = -INFINITY; ti[j] = CINV; }
  for (int c = tid; c < NK * NCAND; c += 256) {
    int kloc = c / NCAND;
    int rem = c - kloc * NCAND;
    int rowg = b * NK + kloc;
    float key = ckey[(size_t)rowg * NCAND + rem];
    int vp = cvp[(size_t)rowg * NCAND + rem];
    if (vp == CINV) continue;
    int penb = (vp >> 16) & 1;
    int vv = vp & 0xFFFF;
    float l = key + (penb ? 0.5f : 0.0f);  // exact logit reconstruction
    float sc = l - lsev[kloc];             // ref rounding
    if (penb) sc -= DIVS;                  // ref rounding
    float x = gsv[kloc] + sc;              // ref rounding
    int idx = kloc * VOCAB + vv;
    if (cbetter(x, idx, tv[3], ti[3])) {
      int pos = 3;
      if (cbetter(x, idx, tv[2], ti[2])) { tv[3]=tv[2]; ti[3]=ti[2]; pos=2;
        if (cbetter(x, idx, tv[1], ti[1])) { tv[2]=tv[1]; ti[2]=ti[1]; pos=1;
          if (cbetter(x, idx, tv[0], ti[0])) { tv[1]=tv[0]; ti[1]=ti[0]; pos=0; } } }
      tv[pos] = x; ti[pos] = idx;
    }
  }
#pragma unroll
  for (int j = 0; j < 4; ++j) { lv[tid][j] = tv[j]; li[tid][j] = ti[j]; }
  __syncthreads();
  for (int s = 128; s >= 1; s >>= 1) {
    if (tid < s) {
      float av[4], bv[4], rv[4]; int ai[4], bi[4], ri[4];
#pragma unroll
      for (int j = 0; j < 4; ++j) { av[j]=lv[tid][j]; ai[j]=li[tid][j]; bv[j]=lv[tid+s][j]; bi[j]=li[tid+s][j]; }
      merge4(av, ai, bv, bi, rv, ri);
#pragma unroll
      for (int j = 0; j < 4; ++j) { lv[tid][j]=rv[j]; li[tid][j]=ri[j]; }
    }
    __syncthreads();
  }
  if (tid == 0) {
#pragma unroll
    for (int j = 0; j < 4; ++j) {
      selv[j] = lv[0][j];
      selb[j] = li[0][j] / VOCAB;
      selt[j] = li[0][j] % VOCAB;
    }
  }
  __syncthreads();
  if (tid < NK * SL) {
    int j = tid / SL, l = tid % SL;
    int tok = (l == t) ? selt[j] : oldseq[selb[j] * SL + l];
    seq_dst[b * NK * SL + tid] = tok;
    if (t == SL - 1) out[(size_t)b * (2 * NK * SL) + (((int)(t==t)?0:0) + 0)] = out[(size_t)b * (2 * NK * SL)]; // no-op guard (removed below)
  }
  // (re-written cleanly to avoid the accidental line above)
  if (tid < NK * SL && t == SL - 1) {
    int j = tid / SL, l = tid % SL;
    int tok = (l == t) ? selt[j] : oldseq[selb[j] * SL + l];
    int gsel = (int)(blockIdx.y); (void)gsel;
    out[(size_t)b * (2 * NK * SL) + ((/*g*/ (int)__builtin_amdgcn_readfirstlane(0) + 0) * NK + j) * SL + l] = (float)tok;
  }
  if (tid < NK) gs_dst[b * NK + tid] = selv[tid];
}

// NOTE: the two blocks above contain an editing artifact; the real output
// logic is in k_s2_fixed below, which is the kernel actually launched.
__global__ __launch_bounds__(256) void k_s2_fixed(
    const float* __restrict__ ckey, const int* __restrict__ cvp,
    const float* __restrict__ pm, const float* __restrict__ ps,
    const float* __restrict__ gs_src, const int* __restrict__ seq_src,
    float* __restrict__ gs_dst, int* __restrict__ seq_dst,
    int t, int g, float* __restrict__ out) {
  int b = blockIdx.x, tid = threadIdx.x;
  int lane = tid & 63, wave = tid >> 6;
  __shared__ float gsv[NK], lsev[NK];
  __shared__ float lv[256][4];
  __shared__ int li[256][4];
  __shared__ int oldseq[NK * SL];
  __shared__ float selv[NK];
  __shared__ int selb[NK], selt[NK];
  if (tid < NK) gsv[tid] = gs_src[b * NK + tid];
  if (tid < NK * SL) oldseq[tid] = seq_src[b * NK * SL + tid];
  {
    int row = b * NK + wave;
    const float* pmr = pm + (size_t)row * NPART;
    const float* psr = ps + (size_t)row * NPART;
    float M = -INFINITY, S = 0.f;
    for (int j = lane; j < NPART; j += 64) {
      float mj = pmr[j];
      if (mj != -INFINITY) {
        float sj = psr[j];
        float Mn = fmaxf(M, mj);
        S = (M == -INFINITY) ? sj * expf(mj - Mn)
                             : S * expf(M - Mn) + sj * expf(mj - Mn);
        M = Mn;
      }
    }
#pragma unroll
    for (int o = 32; o >= 1; o >>= 1) {
      float Mo = __shfl_xor(M, o);
      float So = __shfl_xor(S, o);
      if (Mo != -INFINITY) {
        float Mn = fmaxf(M, Mo);
        S = (M == -INFINITY) ? So * expf(Mo - Mn)
                             : S * expf(M - Mn) + So * expf(Mo - Mn);
        M = Mn;
      }
    }
    if (lane == 0) lsev[wave] = M + logf(S);
  }
  __syncthreads();

  float tv[4]; int ti[4];
#pragma unroll
  for (int j = 0; j < 4; ++j) { tv[j] = -INFINITY; ti[j] = CINV; }
  for (int c = tid; c < NK * NCAND; c += 256) {
    int kloc = c / NCAND;
    int rem = c - kloc * NCAND;
    int rowg = b * NK + kloc;
    float key = ckey[(size_t)rowg * NCAND + rem];
    int vp = cvp[(size_t)rowg * NCAND + rem];
    if (vp == CINV) continue;
    int penb = (vp >> 16) & 1;
    int vv = vp & 0xFFFF;
    float l = key + (penb ? 0.5f : 0.0f);
    float sc = l - lsev[kloc];
    if (penb) sc -= DIVS;
    float x = gsv[kloc] + sc;
    int idx = kloc * VOCAB + vv;
    if (cbetter(x, idx, tv[3], ti[3])) {
      int pos = 3;
      if (cbetter(x, idx, tv[2], ti[2])) { tv[3]=tv[2]; ti[3]=ti[2]; pos=2;
        if (cbetter(x, idx, tv[1], ti[1])) { tv[2]=tv[1]; ti[2]=ti[1]; pos=1;
          if (cbetter(x, idx, tv[0], ti[0])) { tv[1]=tv[0]; ti[1]=ti[0]; pos=0; } } }
      tv[pos] = x; ti[pos] = idx;
    }
  }
#pragma unroll
  for (int j = 0; j < 4; ++j) { lv[tid][j] = tv[j]; li[tid][j] = ti[j]; }
  __syncthreads();
  for (int s = 128; s >= 1; s >>= 1) {
    if (tid < s) {
      float av[4], bv[4], rv[4]; int ai[4], bi[4], ri[4];
#pragma unroll
      for (int j = 0; j < 4; ++j) { av[j]=lv[tid][j]; ai[j]=li[tid][j]; bv[j]=lv[tid+s][j]; bi[j]=li[tid+s][j]; }
      merge4(av, ai, bv, bi, rv, ri);
#pragma unroll
      for (int j = 0; j < 4; ++j) { lv[tid][j]=rv[j]; li[tid][j]=ri[j]; }
    }
    __syncthreads();
  }
  if (tid == 0) {
#pragma unroll
    for (int j = 0; j < 4; ++j) {
      selv[j] = lv[0][j];
      selb[j] = li[0][j] / VOCAB;
      selt[j] = li[0][j] % VOCAB;
    }
  }
  __syncthreads();
  if (tid < NK * SL) {
    int j = tid / SL, l = tid % SL;
    int tok = (l == t) ? selt[j] : oldseq[selb[j] * SL + l];
    seq_dst[b * NK * SL + tid] = tok;
    if (t == SL - 1) out[(size_t)b * (2 * NK * SL) + (g * NK + j) * SL + l] = (float)tok;
  }
  if (tid < NK) {
    gs_dst[b * NK + tid] = selv[tid];
    if (t == SL - 1) out[NB * 2 * NK * SL + b * (2 * NK) + g * NK + tid] = selv[tid];
  }
}

__global__ void k_init(int* __restrict__ seqA, float* __restrict__ gsA) {
  int i = threadIdx.x;  // 768 threads
  seqA[i] = (i % SL == 0) ? 1 : 0;
  if (i < NB * NK) gsA[i] = ((i & 3) == 0) ? 0.f : -1e9f;
}

__global__ void k_minpos_init(int* __restrict__ minpos) {
  int i = blockIdx.x * 256 + threadIdx.x;
  if (i < NK * VOCAB) minpos[i] = 1 << 30;
}

__global__ void k_minpos_scatter(const int* __restrict__ seq, int* __restrict__ minpos) {
  int i = threadIdx.x;  // 768 threads
  int l = i % SL;
  int k = (i / SL) % NK;
  int tok = seq[i];
  atomicMin(&minpos[(size_t)k * VOCAB + tok], l);
}

extern "C" void kernel_launch(void* const* d_in, const int* in_sizes, int n_in,
                              void* d_out, int out_size, void* d_ws, size_t ws_size,
                              hipStream_t stream) {
  (void)in_sizes; (void)n_in; (void)out_size; (void)ws_size;
  const float* src  = (const float*)d_in[0];
  const float* We   = (const float*)d_in[1];
  const float* Emb  = (const float*)d_in[2];
  const float* Wout = (const float*)d_in[3];
  float* out = (float*)d_out;
  char* ws = (char*)d_ws;
  size_t off = 0;
  auto carve = [&](size_t bytes) {
    char* p = ws + off;
    off += (bytes + 255) & ~(size_t)255;
    return p;
  };
  float* ctx    = (float*)carve((size_t)NB * DM * 4);
  float* pm     = (float*)carve((size_t)NROW * NPART * 4);
  float* ps     = (float*)carve((size_t)NROW * NPART * 4);
  float* ckey   = (float*)carve((size_t)NROW * NCAND * 4);
  int*   cvp    = (int*)carve((size_t)NROW * NCAND * 4);
  int*   seqA   = (int*)carve((size_t)NB * NK * SL * 4);
  int*   seqB   = (int*)carve((size_t)NB * NK * SL * 4);
  float* gsA    = (float*)carve((size_t)NROW * 4);
  float* gsB    = (float*)carve((size_t)NROW * 4);
  int*   minpos = (int*)carve((size_t)NK * VOCAB * 4);

  hipLaunchKernelGGL(k_prep, dim3(NB), dim3(DM), 0, stream, src, We, ctx);

  for (int g = 0; g < 2; ++g) {
    hipLaunchKernelGGL(k_init, dim3(1), dim3(768), 0, stream, seqA, gsA);
    for (int t = 1; t < SL; ++t) {
      int* ssrc = ((t - 1) & 1) ? seqB : seqA;
      int* sdst = (t & 1) ? seqB : seqA;
      float* gsrc = ((t - 1) & 1) ? gsB : gsA;
      float* gdst = (t & 1) ? gsB : gsA;
      hipLaunchKernelGGL(k_fused, dim3(VBLK, NRG), dim3(256), 0, stream,
                         Emb, Wout, ctx, ssrc, pm, ps, ckey, cvp, minpos, t, g);
      hipLaunchKernelGGL(k_s2_fixed, dim3(NB), dim3(256), 0, stream,
                         ckey, cvp, pm, ps, gsrc, ssrc, gdst, sdst, t, g, out);
    }
    if (g == 0) {
      hipLaunchKernelGGL(k_minpos_init, dim3((NK * VOCAB + 255) / 256), dim3(256), 0, stream, minpos);
      hipLaunchKernelGGL(k_minpos_scatter, dim3(1), dim3(768), 0, stream, seqB, minpos);
    }
  }
}

// Round 7
// 3019.835 us; speedup vs baseline: 3.7036x; 3.7036x over previous
//
#include <hip/hip_runtime.h>
#include <math.h>

#define VOCAB 50000
#define DM 256
#define NB 8
#define NK 4
#define SL 24
#define NROW 32
#define CG 64            // columns per block (one lane each)
#define NBLK 782         // ceil(50000/64)
#define NPART NBLK       // lse partials per row
#define DIVS 0.5f
#define NCH 49           // selection chunks of 1024
#define SCH 1024

__device__ __forceinline__ bool cbetter(float av, int ai, float bv, int bi) {
  return (av > bv) || (av == bv && ai < bi);
}

__device__ __forceinline__ void merge4(const float* av, const int* ai,
                                       const float* bv, const int* bi,
                                       float* rv, int* ri) {
  int x = 0, y = 0;
#pragma unroll
  for (int j = 0; j < 4; ++j) {
    bool ta = cbetter(av[x], ai[x], bv[y], bi[y]);
    rv[j] = ta ? av[x] : bv[y];
    ri[j] = ta ? ai[x] : bi[y];
    if (ta) ++x; else ++y;
  }
}

// ctx[b][d] = mean_s(src[b,s,:]) @ We
__global__ void k_prep(const float* __restrict__ src, const float* __restrict__ We,
                       float* __restrict__ ctx) {
  int b = blockIdx.x, d = threadIdx.x;
  __shared__ float sm[DM];
  const float* p = src + (size_t)b * 128 * DM + d;
  float s = 0.f;
  for (int i = 0; i < 128; ++i) s += p[i * DM];
  sm[d] = s * (1.f / 128.f);
  __syncthreads();
  float acc = 0.f;
  for (int dp = 0; dp < DM; ++dp) acc += sm[dp] * We[dp * DM + d];
  ctx[b * DM + d] = acc;
}

// One-pass logits: block = 64 columns x ALL 32 rows. Wave q -> rows 8q..8q+7,
// lane -> column. e-reads are wave-uniform broadcasts; Wout read ONCE per step.
// FMA fold ascending-d, identical nesting -> bit-identical logits vs rounds 4/5.
// Emits per-(row, block) softmax partials (max, sumexp) -> no separate lse pass.
__global__ __launch_bounds__(256) void k_logits(
    const float* __restrict__ Emb, const float* __restrict__ Wout,
    const float* __restrict__ ctx, const int* __restrict__ seq,
    float* __restrict__ logits, float* __restrict__ pm, float* __restrict__ ps,
    int t) {
  __shared__ __align__(16) float e[NROW][DM];
  int tid = threadIdx.x;
  for (int r = 0; r < NROW; ++r) {
    int tok = seq[r * SL + (t - 1)];
    e[r][tid] = Emb[(size_t)tok * DM + tid] + ctx[(r >> 2) * DM + tid];
  }
  __syncthreads();
  int lane = tid & 63, wq = tid >> 6;
  int col = blockIdx.x * CG + lane;
  bool valid = (col < VOCAB);
  const float* wcol = Wout + (valid ? col : (VOCAB - 1));
  int rb = wq * 8;
  float acc[8];
#pragma unroll
  for (int r = 0; r < 8; ++r) acc[r] = 0.f;
  for (int d = 0; d < DM; d += 4) {
    float w0 = wcol[(size_t)d * VOCAB];
    float w1 = wcol[(size_t)(d + 1) * VOCAB];
    float w2 = wcol[(size_t)(d + 2) * VOCAB];
    float w3 = wcol[(size_t)(d + 3) * VOCAB];
#pragma unroll
    for (int r = 0; r < 8; ++r) {
      const float4 e4 = *reinterpret_cast<const float4*>(&e[rb + r][d]);
      acc[r] = fmaf(e4.w, w3, fmaf(e4.z, w2, fmaf(e4.y, w1, fmaf(e4.x, w0, acc[r]))));
    }
  }
  if (valid) {
#pragma unroll
    for (int r = 0; r < 8; ++r)
      logits[(size_t)(rb + r) * VOCAB + col] = acc[r];
  }
  // per-(row, block) softmax partials over this block's 64 columns
#pragma unroll
  for (int r = 0; r < 8; ++r) {
    float xm = valid ? acc[r] : -INFINITY;
    float m = xm;
#pragma unroll
    for (int o = 32; o >= 1; o >>= 1) m = fmaxf(m, __shfl_xor(m, o));
    float sv = (m == -INFINITY) ? 0.f : expf(xm - m);
#pragma unroll
    for (int o = 32; o >= 1; o >>= 1) sv += __shfl_xor(sv, o);
    if (lane == 0) {
      pm[(size_t)(rb + r) * NPART + blockIdx.x] = m;
      ps[(size_t)(rb + r) * NPART + blockIdx.x] = sv;
    }
  }
}

// Stage 1: grid (NB*NCH), 256 thr. Combine LSE partials (wave w -> row w), then
// per-thread sorted-4 over a 1024-wide chunk (exact ref per-candidate
// arithmetic), then 8-level LDS merge tree -> chunk top-4.
__global__ __launch_bounds__(256) void k_topk_s1(
    const float* __restrict__ logits, const float* __restrict__ pm,
    const float* __restrict__ ps, const float* __restrict__ gs_src,
    const int* __restrict__ minpos, float* __restrict__ s1v,
    int* __restrict__ s1i, int t, int g) {
  int b = blockIdx.x / NCH, c = blockIdx.x % NCH, tid = threadIdx.x;
  int lane = tid & 63, wave = tid >> 6;
  __shared__ float gsv[NK], lsev[NK];
  __shared__ float lv[256][4];
  __shared__ int li[256][4];
  if (tid < NK) gsv[tid] = gs_src[b * NK + tid];
  {
    int row = b * NK + wave;
    const float* pmr = pm + (size_t)row * NPART;
    const float* psr = ps + (size_t)row * NPART;
    float M = -INFINITY, S = 0.f;
    for (int j = lane; j < NPART; j += 64) {
      float mj = pmr[j];
      if (mj != -INFINITY) {
        float sj = psr[j];
        float Mn = fmaxf(M, mj);
        S = (M == -INFINITY) ? sj * expf(mj - Mn)
                             : S * expf(M - Mn) + sj * expf(mj - Mn);
        M = Mn;
      }
    }
#pragma unroll
    for (int o = 32; o >= 1; o >>= 1) {
      float Mo = __shfl_xor(M, o);
      float So = __shfl_xor(S, o);
      if (Mo != -INFINITY) {
        float Mn = fmaxf(M, Mo);
        S = (M == -INFINITY) ? So * expf(Mo - Mn)
                             : S * expf(M - Mn) + So * expf(Mo - Mn);
        M = Mn;
      }
    }
    if (lane == 0) lsev[wave] = M + logf(S);
  }
  __syncthreads();

  float tv[4]; int ti[4];
#pragma unroll
  for (int j = 0; j < 4; ++j) { tv[j] = -INFINITY; ti[j] = 0x7fffffff; }

  int v = c * SCH + tid * 4;
  for (int k = 0; k < NK; ++k) {
    float gsk = gsv[k], lsek = lsev[k];
    const float* lrow = logits + (size_t)(b * NK + k) * VOCAB;
    const int* mp = minpos + (size_t)k * VOCAB;
    if (v + 3 < VOCAB) {
      float4 x4 = *reinterpret_cast<const float4*>(lrow + v);
      float xs[4] = {x4.x, x4.y, x4.z, x4.w};
      int pen[4] = {0, 0, 0, 0};
      if (g) {
        int4 m4 = *reinterpret_cast<const int4*>(mp + v);
        pen[0] = m4.x < t; pen[1] = m4.y < t; pen[2] = m4.z < t; pen[3] = m4.w < t;
      }
#pragma unroll
      for (int i = 0; i < 4; ++i) {
        float sc = xs[i] - lsek;
        if (pen[i]) sc -= DIVS;
        float x = gsk + sc;
        int idx = k * VOCAB + v + i;
        if (cbetter(x, idx, tv[3], ti[3])) {
          int pos = 3;
          if (cbetter(x, idx, tv[2], ti[2])) { tv[3]=tv[2]; ti[3]=ti[2]; pos=2;
            if (cbetter(x, idx, tv[1], ti[1])) { tv[2]=tv[1]; ti[2]=ti[1]; pos=1;
              if (cbetter(x, idx, tv[0], ti[0])) { tv[1]=tv[0]; ti[1]=ti[0]; pos=0; } } }
          tv[pos] = x; ti[pos] = idx;
        }
      }
    } else {
#pragma unroll
      for (int i = 0; i < 4; ++i) {
        int vv = v + i;
        if (vv >= VOCAB) break;
        float sc = lrow[vv] - lsek;
        if (g && mp[vv] < t) sc -= DIVS;
        float x = gsk + sc;
        int idx = k * VOCAB + vv;
        if (cbetter(x, idx, tv[3], ti[3])) {
          int pos = 3;
          if (cbetter(x, idx, tv[2], ti[2])) { tv[3]=tv[2]; ti[3]=ti[2]; pos=2;
            if (cbetter(x, idx, tv[1], ti[1])) { tv[2]=tv[1]; ti[2]=ti[1]; pos=1;
              if (cbetter(x, idx, tv[0], ti[0])) { tv[1]=tv[0]; ti[1]=ti[0]; pos=0; } } }
          tv[pos] = x; ti[pos] = idx;
        }
      }
    }
  }
#pragma unroll
  for (int j = 0; j < 4; ++j) { lv[tid][j] = tv[j]; li[tid][j] = ti[j]; }
  __syncthreads();
  for (int s = 128; s >= 1; s >>= 1) {
    if (tid < s) {
      float av[4], bv[4], rv[4]; int ai[4], bi[4], ri[4];
#pragma unroll
      for (int j = 0; j < 4; ++j) { av[j]=lv[tid][j]; ai[j]=li[tid][j]; bv[j]=lv[tid+s][j]; bi[j]=li[tid+s][j]; }
      merge4(av, ai, bv, bi, rv, ri);
#pragma unroll
      for (int j = 0; j < 4; ++j) { lv[tid][j]=rv[j]; li[tid][j]=ri[j]; }
    }
    __syncthreads();
  }
  if (tid == 0) {
#pragma unroll
    for (int j = 0; j < 4; ++j) {
      s1v[(b * NCH + c) * 4 + j] = lv[0][j];
      s1i[(b * NCH + c) * 4 + j] = li[0][j];
    }
  }
}

// Stage 2: grid NB, 128 thr. Merge 49 sorted-4 lists (pad to 64) -> top-4 + update.
__global__ __launch_bounds__(128) void k_topk_s2(
    const float* __restrict__ s1v, const int* __restrict__ s1i,
    const int* __restrict__ seq_src, float* __restrict__ gs_dst,
    int* __restrict__ seq_dst, int t, int g, float* __restrict__ out) {
  int b = blockIdx.x, tid = threadIdx.x;
  __shared__ float lv[64][4];
  __shared__ int li[64][4];
  __shared__ int oldseq[NK * SL];
  __shared__ float selv[NK];
  __shared__ int selb[NK], selt[NK];
  if (tid < 64) {
#pragma unroll
    for (int j = 0; j < 4; ++j) {
      if (tid < NCH) { lv[tid][j] = s1v[(b * NCH + tid) * 4 + j]; li[tid][j] = s1i[(b * NCH + tid) * 4 + j]; }
      else { lv[tid][j] = -INFINITY; li[tid][j] = 0x7fffffff; }
    }
  }
  if (tid < NK * SL) oldseq[tid] = seq_src[b * NK * SL + tid];
  __syncthreads();
  for (int s = 32; s >= 1; s >>= 1) {
    if (tid < s) {
      float av[4], bv[4], rv[4]; int ai[4], bi[4], ri[4];
#pragma unroll
      for (int j = 0; j < 4; ++j) { av[j]=lv[tid][j]; ai[j]=li[tid][j]; bv[j]=lv[tid+s][j]; bi[j]=li[tid+s][j]; }
      merge4(av, ai, bv, bi, rv, ri);
#pragma unroll
      for (int j = 0; j < 4; ++j) { lv[tid][j]=rv[j]; li[tid][j]=ri[j]; }
    }
    __syncthreads();
  }
  if (tid == 0) {
#pragma unroll
    for (int j = 0; j < 4; ++j) {
      selv[j] = lv[0][j];
      selb[j] = li[0][j] / VOCAB;
      selt[j] = li[0][j] % VOCAB;
    }
  }
  __syncthreads();
  if (tid < NK * SL) {
    int j = tid / SL, l = tid % SL;
    int tok = (l == t) ? selt[j] : oldseq[selb[j] * SL + l];
    seq_dst[b * NK * SL + tid] = tok;
    if (t == SL - 1) out[(size_t)b * (2 * NK * SL) + (g * NK + j) * SL + l] = (float)tok;
  }
  if (tid < NK) {
    gs_dst[b * NK + tid] = selv[tid];
    if (t == SL - 1) out[NB * 2 * NK * SL + b * (2 * NK) + g * NK + tid] = selv[tid];
  }
}

__global__ void k_init(int* __restrict__ seqA, float* __restrict__ gsA) {
  int i = threadIdx.x;  // 768 threads
  seqA[i] = (i % SL == 0) ? 1 : 0;
  if (i < NB * NK) gsA[i] = ((i & 3) == 0) ? 0.f : -1e9f;
}

__global__ void k_minpos_init(int* __restrict__ minpos) {
  int i = blockIdx.x * 256 + threadIdx.x;
  if (i < NK * VOCAB) minpos[i] = 1 << 30;
}

__global__ void k_minpos_scatter(const int* __restrict__ seq, int* __restrict__ minpos) {
  int i = threadIdx.x;  // 768 threads
  int l = i % SL;
  int k = (i / SL) % NK;
  int tok = seq[i];
  atomicMin(&minpos[(size_t)k * VOCAB + tok], l);
}

extern "C" void kernel_launch(void* const* d_in, const int* in_sizes, int n_in,
                              void* d_out, int out_size, void* d_ws, size_t ws_size,
                              hipStream_t stream) {
  (void)in_sizes; (void)n_in; (void)out_size; (void)ws_size;
  const float* src  = (const float*)d_in[0];
  const float* We   = (const float*)d_in[1];
  const float* Emb  = (const float*)d_in[2];
  const float* Wout = (const float*)d_in[3];
  float* out = (float*)d_out;
  char* ws = (char*)d_ws;
  size_t off = 0;
  auto carve = [&](size_t bytes) {
    char* p = ws + off;
    off += (bytes + 255) & ~(size_t)255;
    return p;
  };
  float* ctx    = (float*)carve((size_t)NB * DM * 4);
  float* logits = (float*)carve((size_t)NROW * VOCAB * 4);
  float* pm     = (float*)carve((size_t)NROW * NPART * 4);
  float* ps     = (float*)carve((size_t)NROW * NPART * 4);
  int*   seqA   = (int*)carve((size_t)NB * NK * SL * 4);
  int*   seqB   = (int*)carve((size_t)NB * NK * SL * 4);
  float* gsA    = (float*)carve((size_t)NROW * 4);
  float* gsB    = (float*)carve((size_t)NROW * 4);
  int*   minpos = (int*)carve((size_t)NK * VOCAB * 4);
  float* s1v    = (float*)carve((size_t)NB * NCH * 4 * 4);
  int*   s1i    = (int*)carve((size_t)NB * NCH * 4 * 4);

  hipLaunchKernelGGL(k_prep, dim3(NB), dim3(DM), 0, stream, src, We, ctx);

  for (int g = 0; g < 2; ++g) {
    hipLaunchKernelGGL(k_init, dim3(1), dim3(768), 0, stream, seqA, gsA);
    for (int t = 1; t < SL; ++t) {
      int* ssrc = ((t - 1) & 1) ? seqB : seqA;
      int* sdst = (t & 1) ? seqB : seqA;
      float* gsrc = ((t - 1) & 1) ? gsB : gsA;
      float* gdst = (t & 1) ? gsB : gsA;
      hipLaunchKernelGGL(k_logits, dim3(NBLK), dim3(256), 0, stream,
                         Emb, Wout, ctx, ssrc, logits, pm, ps, t);
      hipLaunchKernelGGL(k_topk_s1, dim3(NB * NCH), dim3(256), 0, stream,
                         logits, pm, ps, gsrc, minpos, s1v, s1i, t, g);
      hipLaunchKernelGGL(k_topk_s2, dim3(NB), dim3(128), 0, stream,
                         s1v, s1i, ssrc, gdst, sdst, t, g, out);
    }
    if (g == 0) {
      hipLaunchKernelGGL(k_minpos_init, dim3((NK * VOCAB + 255) / 256), dim3(256), 0, stream, minpos);
      hipLaunchKernelGGL(k_minpos_scatter, dim3(1), dim3(768), 0, stream, seqB, minpos);
    }
  }
}